// Round 11
// baseline (1043.430 us; speedup 1.0000x reference)
//
#include <hip/hip_runtime.h>
#include <hip/hip_bf16.h>

#define B_ 4
#define S_ 2048
#define DIN 2048
#define DST 2048
#define DOUT 2048
#define NH 16
#define HH 128
#define M_ (B_ * S_)          // 8192
#define OUT_OFF ((size_t)M_ * DOUT)  // 16777216

typedef __attribute__((ext_vector_type(8))) __bf16 bf16x8;
typedef __attribute__((ext_vector_type(4))) float f32x4;
typedef __attribute__((ext_vector_type(2))) _Float16 f16x2;

__device__ __forceinline__ unsigned short f2bf(float f) {
    unsigned int u = __float_as_uint(f);
    unsigned int r = u + 0x7FFFu + ((u >> 16) & 1u);
    return (unsigned short)(r >> 16);
}
__device__ __forceinline__ unsigned pk16(_Float16 a, _Float16 b) {
    return (unsigned)__builtin_bit_cast(unsigned short, a) |
           ((unsigned)__builtin_bit_cast(unsigned short, b) << 16);
}

__device__ __forceinline__ float fdot2(f16x2 a, f16x2 b, float c) {
#if __has_builtin(__builtin_amdgcn_fdot2)
    return __builtin_amdgcn_fdot2(a, b, c, false);
#else
    return fmaf((float)a.x, (float)b.x, fmaf((float)a.y, (float)b.y, c));
#endif
}
__device__ __forceinline__ float fdu(unsigned h, unsigned w, float c) {
    return fdot2(__builtin_bit_cast(f16x2, h), __builtin_bit_cast(f16x2, w), c);
}

__device__ __forceinline__ void gload_lds16(const void* g, void* l) {
    __builtin_amdgcn_global_load_lds(
        (const __attribute__((address_space(1))) void*)g,
        (__attribute__((address_space(3))) void*)l, 16, 0, 0);
}

// ------------- transpose + cast: in[K][N] fp32 -> out[N][K] bf16 -------------
__global__ __launch_bounds__(256) void k_transpose_bf16(
    const float* __restrict__ in, unsigned short* __restrict__ out, int K, int N) {
    __shared__ float tile[64][65];
    int k0 = blockIdx.y * 64, n0 = blockIdx.x * 64;
    int tr  = threadIdx.x >> 4;
    int tc4 = (threadIdx.x & 15) * 4;
#pragma unroll
    for (int p = 0; p < 4; ++p) {
        int r = tr + p * 16;
        float4 v = *(const float4*)&in[(size_t)(k0 + r) * N + n0 + tc4];
        tile[r][tc4 + 0] = v.x; tile[r][tc4 + 1] = v.y;
        tile[r][tc4 + 2] = v.z; tile[r][tc4 + 3] = v.w;
    }
    __syncthreads();
#pragma unroll
    for (int p = 0; p < 4; ++p) {
        int n = tr + p * 16;
        ushort4 o;
        o.x = f2bf(tile[tc4 + 0][n]); o.y = f2bf(tile[tc4 + 1][n]);
        o.z = f2bf(tile[tc4 + 2][n]); o.w = f2bf(tile[tc4 + 3][n]);
        *(ushort4*)&out[(size_t)(n0 + n) * K + k0 + tc4] = o;
    }
}

// ------ GEMM1: xp(f16) = cast(x fp32) @ wit^T + bias ; reg-staged A cast ------
__global__ __launch_bounds__(256, 2) void k_gemm1(
    const float* __restrict__ x,
    const unsigned short* __restrict__ Bt,
    unsigned short* __restrict__ xpf,
    const float* __restrict__ bias) {
    __shared__ unsigned short As[128 * 64];
    __shared__ unsigned short Bs[128 * 64];
    const int tid  = threadIdx.x;
    const int lane = tid & 63;
    const int wid  = tid >> 6;
    const int wr = wid >> 1, wc = wid & 1;
    const int row0 = blockIdx.y * 128, col0 = blockIdx.x * 128;

    f32x4 acc[4][4];
#pragma unroll
    for (int m = 0; m < 4; ++m)
#pragma unroll
        for (int n = 0; n < 4; ++n) acc[m][n] = (f32x4)(0.f);

    const float* Ab = x + (size_t)row0 * DIN;
    const char* Bb = (const char*)(Bt + (size_t)col0 * DIN);

    int srow[4], skb[4];
#pragma unroll
    for (int i = 0; i < 4; ++i) {
        unsigned o = (unsigned)(i * 256 + tid) * 16u;
        unsigned l = o ^ (((o >> 7) & 7u) << 4);
        srow[i] = (int)(l >> 7);
        skb[i]  = (int)(l & 127u);
    }

    for (int kt = 0; kt < DIN; kt += 64) {
#pragma unroll
        for (int i = 0; i < 8; ++i) {
            int idx = i * 256 + tid;
            int row = idx >> 4;
            int cc  = (idx & 15) * 4;
            float4 v = *(const float4*)&Ab[(size_t)row * DIN + kt + cc];
            ushort4 u;
            u.x = f2bf(v.x); u.y = f2bf(v.y); u.z = f2bf(v.z); u.w = f2bf(v.w);
            unsigned byte = (unsigned)(row * 128 + cc * 2);
            byte ^= ((unsigned)(row & 7)) << 4;
            *(ushort4*)((char*)As + byte) = u;
        }
#pragma unroll
        for (int i = 0; i < 4; ++i) {
            unsigned o = (unsigned)(i * 256 + tid) * 16u;
            gload_lds16(Bb + (size_t)srow[i] * (DIN * 2) + (size_t)kt * 2 + skb[i],
                        (char*)Bs + o);
        }
        asm volatile("s_waitcnt vmcnt(0)" ::: "memory");
        __syncthreads();
#pragma unroll
        for (int ks = 0; ks < 2; ++ks) {
            bf16x8 af[4], bfr[4];
#pragma unroll
            for (int m = 0; m < 4; ++m) {
                int row = wr * 64 + m * 16 + (lane & 15);
                unsigned o = (unsigned)(row * 128 + ks * 64 + ((lane >> 4) * 16));
                o ^= ((unsigned)(row & 7) << 4);
                af[m] = *(const bf16x8*)((const char*)As + o);
            }
#pragma unroll
            for (int n = 0; n < 4; ++n) {
                int col = wc * 64 + n * 16 + (lane & 15);
                unsigned o = (unsigned)(col * 128 + ks * 64 + ((lane >> 4) * 16));
                o ^= ((unsigned)(col & 7) << 4);
                bfr[n] = *(const bf16x8*)((const char*)Bs + o);
            }
#pragma unroll
            for (int m = 0; m < 4; ++m)
#pragma unroll
                for (int n = 0; n < 4; ++n)
                    acc[m][n] = __builtin_amdgcn_mfma_f32_16x16x32_bf16(
                        af[m], bfr[n], acc[m][n], 0, 0, 0);
        }
        __syncthreads();
    }

#pragma unroll
    for (int n = 0; n < 4; ++n) {
        int gcol = col0 + wc * 64 + n * 16 + (lane & 15);
        float bv = bias[gcol];
#pragma unroll
        for (int m = 0; m < 4; ++m) {
            int growb = row0 + wr * 64 + m * 16 + ((lane >> 4) * 4);
#pragma unroll
            for (int r = 0; r < 4; ++r) {
                float v = acc[m][n][r] + bv;
                xpf[(size_t)(growb + r) * DST + gcol] =
                    __builtin_bit_cast(unsigned short, (_Float16)v);
            }
        }
    }
}

// ---------------- GEMM2: out(f32) = hs(bf16) @ wot^T ----------------
__global__ __launch_bounds__(256, 2) void k_gemm2(
    const unsigned short* __restrict__ A,
    const unsigned short* __restrict__ Bt,
    float* __restrict__ C) {
    __shared__ unsigned short As[128 * 64];
    __shared__ unsigned short Bs[128 * 64];
    const int tid  = threadIdx.x;
    const int lane = tid & 63;
    const int wid  = tid >> 6;
    const int wr = wid >> 1, wc = wid & 1;
    const int row0 = blockIdx.y * 128, col0 = blockIdx.x * 128;

    f32x4 acc[4][4];
#pragma unroll
    for (int m = 0; m < 4; ++m)
#pragma unroll
        for (int n = 0; n < 4; ++n) acc[m][n] = (f32x4)(0.f);

    const char* Abase = (const char*)(A + (size_t)row0 * DST);
    const char* Bbase = (const char*)(Bt + (size_t)col0 * DST);

    int srow[4], skb[4];
#pragma unroll
    for (int i = 0; i < 4; ++i) {
        unsigned o = (unsigned)(i * 256 + tid) * 16u;
        unsigned l = o ^ (((o >> 7) & 7u) << 4);
        srow[i] = (int)(l >> 7);
        skb[i]  = (int)(l & 127u);
    }

    for (int kt = 0; kt < DST; kt += 64) {
#pragma unroll
        for (int i = 0; i < 4; ++i) {
            unsigned o = (unsigned)(i * 256 + tid) * 16u;
            gload_lds16(Abase + (size_t)srow[i] * (DST * 2) + (size_t)kt * 2 + skb[i],
                        (char*)As + o);
            gload_lds16(Bbase + (size_t)srow[i] * (DST * 2) + (size_t)kt * 2 + skb[i],
                        (char*)Bs + o);
        }
        asm volatile("s_waitcnt vmcnt(0)" ::: "memory");
        __syncthreads();
#pragma unroll
        for (int ks = 0; ks < 2; ++ks) {
            bf16x8 af[4], bfr[4];
#pragma unroll
            for (int m = 0; m < 4; ++m) {
                int row = wr * 64 + m * 16 + (lane & 15);
                unsigned o = (unsigned)(row * 128 + ks * 64 + ((lane >> 4) * 16));
                o ^= ((unsigned)(row & 7) << 4);
                af[m] = *(const bf16x8*)((const char*)As + o);
            }
#pragma unroll
            for (int n = 0; n < 4; ++n) {
                int col = wc * 64 + n * 16 + (lane & 15);
                unsigned o = (unsigned)(col * 128 + ks * 64 + ((lane >> 4) * 16));
                o ^= ((unsigned)(col & 7) << 4);
                bfr[n] = *(const bf16x8*)((const char*)Bs + o);
            }
#pragma unroll
            for (int m = 0; m < 4; ++m)
#pragma unroll
                for (int n = 0; n < 4; ++n)
                    acc[m][n] = __builtin_amdgcn_mfma_f32_16x16x32_bf16(
                        af[m], bfr[n], acc[m][n], 0, 0, 0);
        }
        __syncthreads();
    }

#pragma unroll
    for (int n = 0; n < 4; ++n) {
        int gcol = col0 + wc * 64 + n * 16 + (lane & 15);
#pragma unroll
        for (int m = 0; m < 4; ++m) {
            int growb = row0 + wr * 64 + m * 16 + ((lane >> 4) * 4);
            float* cp = C + (size_t)growb * DOUT + gcol;
#pragma unroll
            for (int r = 0; r < 4; ++r) cp[(size_t)r * DOUT] = acc[m][n][r];
        }
    }
}

// ---------------- RNN scan v11: single wave, ALL W in VGPRs, anti-remat ----------------
// 64 blocks x 64 threads (1 wave/chain). Lane owns cols 2l, 2l+1; all 128
// weight row-pairs live in 128 f16x2 VGPRs, each PINNED via inline-asm def
// (asm outputs are never rematerialized -> no per-step reloads, the r6 bug).
// Per step: 16 broadcast ds_read_b128 of h (single addr = conflict-free),
// 128 fdot2 in 8 independent chains, tanh x2, one ds_write. NO barrier,
// NO DPP: single-wave DS pipe ordering guarantees read-after-write.
__global__ __attribute__((amdgpu_flat_work_group_size(64, 64),
                          amdgpu_waves_per_eu(1, 1))) void k_scan(
    const unsigned short* __restrict__ xpf,  // f16 [M_][DST]
    const float* __restrict__ h0,            // [B_][DST]
    const float* __restrict__ sw,            // [NH][HH][HH]
    unsigned short* __restrict__ hsb,        // bf16 [M_][DST]
    float* __restrict__ out_state) {         // [B_][DST]
    __shared__ __align__(16) unsigned hb[64];
    const int l = threadIdx.x;                // 0..63
    const int bb = blockIdx.x >> 4;
    const int nn = blockIdx.x & 15;
    const int c0 = l * 2;

    const float* wb = sw + (size_t)nn * HH * HH;

    // wu[k]    = (W[2k][c0],   W[2k+1][c0])   k=0..63  (col c0)
    // wu[64+k] = (W[2k][c0+1], W[2k+1][c0+1])          (col c0+1)
    unsigned wu[128];
#pragma unroll
    for (int k = 0; k < 64; ++k) {
        float2 rA = *(const float2*)&wb[(size_t)(2 * k) * HH + c0];
        float2 rB = *(const float2*)&wb[(size_t)(2 * k + 1) * HH + c0];
        unsigned a = pk16((_Float16)rA.x, (_Float16)rB.x);
        unsigned b = pk16((_Float16)rA.y, (_Float16)rB.y);
        asm volatile("" : "+v"(a));   // pin: non-rematerializable def
        asm volatile("" : "+v"(b));
        wu[k] = a;
        wu[64 + k] = b;
    }

    {   // h init: dword l = (h[2l], h[2l+1]) f16
        float2 h2 = *(const float2*)&h0[bb * DST + nn * HH + c0];
        hb[l] = pk16((_Float16)h2.x, (_Float16)h2.y);
    }

    const unsigned* xrow = (const unsigned*)(xpf + (size_t)bb * S_ * DST + nn * HH) + l;
    unsigned* hrow = (unsigned*)(hsb + (size_t)bb * S_ * DST + nn * HH) + l;
    float* osp = out_state + bb * DST + nn * HH + c0;

    unsigned x0 = xrow[0], x1 = xrow[1024], x2 = xrow[2048], x3 = xrow[3072];

    const uint4* hp = (const uint4*)hb;

    for (int t = 0; t < S_; ++t) {
        int tpf = (t + 4 < S_) ? t + 4 : S_ - 1;
        unsigned x4 = xrow[(size_t)tpf * 1024];

        float a0 = 0.f, a1 = 0.f, a2 = 0.f, a3 = 0.f;
        float b0 = 0.f, b1 = 0.f, b2 = 0.f, b3 = 0.f;
#pragma unroll
        for (int j = 0; j < 16; ++j) {
            uint4 H = hp[j];
            a0 = fdu(H.x, wu[4 * j + 0], a0); b0 = fdu(H.x, wu[64 + 4 * j + 0], b0);
            a1 = fdu(H.y, wu[4 * j + 1], a1); b1 = fdu(H.y, wu[64 + 4 * j + 1], b1);
            a2 = fdu(H.z, wu[4 * j + 2], a2); b2 = fdu(H.z, wu[64 + 4 * j + 2], b2);
            a3 = fdu(H.w, wu[4 * j + 3], a3); b3 = fdu(H.w, wu[64 + 4 * j + 3], b3);
        }

        f16x2 xv = __builtin_bit_cast(f16x2, x0);
        float s0 = ((a0 + a1) + (a2 + a3)) + (float)xv.x;
        float s1 = ((b0 + b1) + (b2 + b3)) + (float)xv.y;
        // tanh(s) = 1 - 2/(exp(2s)+1), exact at +-inf
        float e0 = __builtin_amdgcn_exp2f(s0 * 2.885390081777927f);
        float e1 = __builtin_amdgcn_exp2f(s1 * 2.885390081777927f);
        float th0 = fmaf(-2.f, __builtin_amdgcn_rcpf(e0 + 1.f), 1.f);
        float th1 = fmaf(-2.f, __builtin_amdgcn_rcpf(e1 + 1.f), 1.f);

        // single wave: in-order DS pipe makes this write safe, no barrier.
        hb[l] = pk16((_Float16)th0, (_Float16)th1);
        hrow[(size_t)t * (DST / 2)] = (unsigned)f2bf(th0) | ((unsigned)f2bf(th1) << 16);
        if (t == S_ - 1) { osp[0] = th0; osp[1] = th1; }

        x0 = x1; x1 = x2; x2 = x3; x3 = x4;
    }
}

extern "C" void kernel_launch(void* const* d_in, const int* in_sizes, int n_in,
                              void* d_out, int out_size, void* d_ws, size_t ws_size,
                              hipStream_t stream) {
    const float* x    = (const float*)d_in[0];
    const float* h0   = (const float*)d_in[1];
    const float* Wi   = (const float*)d_in[2];
    const float* bias = (const float*)d_in[3];
    const float* sw   = (const float*)d_in[4];
    const float* Wo   = (const float*)d_in[5];
    float* out = (float*)d_out;

    char* ws = (char*)d_ws;
    unsigned short* hsb = (unsigned short*)ws;                 // 32MB bf16 hs
    unsigned short* wit = (unsigned short*)(ws + 33554432);    // 8MB
    unsigned short* wot = (unsigned short*)(ws + 41943040);    // 8MB
    unsigned short* xpf = (unsigned short*)(ws + 50331648);    // 32MB f16 xp

    // 1. transpose+cast weights
    dim3 tg(32, 32);
    k_transpose_bf16<<<tg, 256, 0, stream>>>(Wi, wit, DIN, DST);
    k_transpose_bf16<<<tg, 256, 0, stream>>>(Wo, wot, DST, DOUT);
    // 2. xp(f16) = cast(x) @ Wi + b   (fused cast, reg-staged A)
    dim3 g1(DST / 128, M_ / 128);
    k_gemm1<<<g1, 256, 0, stream>>>(x, wit, xpf, bias);
    // 3. sequential scan (1 wave per chain, all-W-in-VGPR)
    k_scan<<<64, 64, 0, stream>>>(xpf, h0, sw, hsb, out + OUT_OFF);
    // 4. out = hs @ Wo
    dim3 g2(DOUT / 128, M_ / 128);
    k_gemm2<<<g2, 256, 0, stream>>>(hsb, wot, out);
}